// Round 19
// baseline (42.944 us; speedup 1.0000x reference)
//
#include <hip/hip_runtime.h>
#include <hip/hip_bf16.h>

#define BB 4096
#define DD 512

typedef unsigned short u16;
typedef unsigned int u32;
typedef signed char s8;

using f32x4 = __attribute__((ext_vector_type(4))) float;
using i32x4 = __attribute__((ext_vector_type(4))) int;

// int8 quant: q = rint(x_norm * QS); exact i32 dot, s ~= acc / QS^2.
// p = exp2((s-1)*100*log2e + 64) = exp2(acc*CEXPQ + EOFF); lse = 100 - 64*ln2 + ln(sum p)
constexpr float QS = 400.0f;
constexpr float CEXP = 144.26950408889634f;          // 100 * log2(e)
constexpr float CEXPQ = CEXP / (QS * QS);            // dequant folded in
constexpr float EOFF = 64.0f - 144.26950408889634f;  // bias - CEXP
constexpr float LN2 = 0.6931471805599453f;
constexpr float LSE_BASE = 100.0f - 64.0f * 0.6931471805599453f;

__device__ __forceinline__ float wave_sum(float v) {
#pragma unroll
  for (int m = 1; m < 64; m <<= 1) v += __shfl_xor(v, m);
  return v;
}

// async global->LDS, 16B per lane. LDS dest is wave-uniform base + lane*16.
__device__ __forceinline__ void gload16(const void* g, const void* l) {
  __builtin_amdgcn_global_load_lds(
      (const __attribute__((address_space(1))) void*)g,
      (__attribute__((address_space(3))) void*)(const_cast<void*>(l)), 16, 0, 0);
}

// raw barrier (no vmcnt/lgkmcnt drain); memory clobbers pin memory ops to their side
__device__ __forceinline__ void barrier_raw() {
  asm volatile("" ::: "memory");
  __builtin_amdgcn_s_barrier();
  asm volatile("" ::: "memory");
}

__device__ __forceinline__ u32 q4(float a, float b, float c, float d, float s) {
  const int qa = (int)rintf(fminf(fmaxf(a * s, -127.0f), 127.0f));
  const int qb = (int)rintf(fminf(fmaxf(b * s, -127.0f), 127.0f));
  const int qc = (int)rintf(fminf(fmaxf(c * s, -127.0f), 127.0f));
  const int qd = (int)rintf(fminf(fmaxf(d * s, -127.0f), 127.0f));
  return (qa & 0xff) | ((qb & 0xff) << 8) | ((qc & 0xff) << 16) | ((qd & 0xff) << 24);
}

// ---------------- kernel 1: row L2-normalize (fp32) -> int8 (scale QS), fp32 pos ----------------
// Also zeroes out[0] each call (k_final accumulates into it atomically; keeps graph
// replays self-contained).
__global__ __launch_bounds__(256) void k_norm(const float* __restrict__ feat,
                                              const float* __restrict__ feat_old,
                                              s8* __restrict__ fn8, s8* __restrict__ fo8,
                                              float* __restrict__ pos,
                                              float* __restrict__ out) {
  if (blockIdx.x == 0 && threadIdx.x == 0) out[0] = 0.0f;
  const int i = blockIdx.x * 4 + (threadIdx.x >> 6);
  const int t = threadIdx.x & 63;
  const float4 x0 = *(const float4*)(feat + (size_t)i * DD + t * 4);
  const float4 x1 = *(const float4*)(feat + (size_t)i * DD + 256 + t * 4);
  const float4 y0 = *(const float4*)(feat_old + (size_t)i * DD + t * 4);
  const float4 y1 = *(const float4*)(feat_old + (size_t)i * DD + 256 + t * 4);
  float sx = x0.x * x0.x + x0.y * x0.y + x0.z * x0.z + x0.w * x0.w +
             x1.x * x1.x + x1.y * x1.y + x1.z * x1.z + x1.w * x1.w;
  float sy = y0.x * y0.x + y0.y * y0.y + y0.z * y0.z + y0.w * y0.w +
             y1.x * y1.x + y1.y * y1.y + y1.z * y1.z + y1.w * y1.w;
  float sxy = x0.x * y0.x + x0.y * y0.y + x0.z * y0.z + x0.w * y0.w +
              x1.x * y1.x + x1.y * y1.y + x1.z * y1.z + x1.w * y1.w;
  sx = wave_sum(sx);
  sy = wave_sum(sy);
  sxy = wave_sum(sxy);
  const float inx = 1.0f / fmaxf(sqrtf(sx), 1e-12f);
  const float iny = 1.0f / fmaxf(sqrtf(sy), 1e-12f);
  const float sxq = inx * QS, syq = iny * QS;
  u32* px0 = (u32*)(fn8 + (size_t)i * DD + t * 4);
  u32* px1 = (u32*)(fn8 + (size_t)i * DD + 256 + t * 4);
  u32* py0 = (u32*)(fo8 + (size_t)i * DD + t * 4);
  u32* py1 = (u32*)(fo8 + (size_t)i * DD + 256 + t * 4);
  *px0 = q4(x0.x, x0.y, x0.z, x0.w, sxq);
  *px1 = q4(x1.x, x1.y, x1.z, x1.w, sxq);
  *py0 = q4(y0.x, y0.y, y0.z, y0.w, syq);
  *py1 = q4(y1.x, y1.y, y1.z, y1.w, syq);
  if (t == 0) pos[i] = sxy * inx * iny;  // exact fp32 positive logit
}

// ---------------- kernel 2: fused dual-GEMM, int8 MFMA (champion loop + XCD-rect map) ----------------
// 512 blocks; XCD x (blockIdx%8) owns an 8mt x 8nt RECT of the 16x32 tile grid:
// per-XCD working set = A 8x256 rows (1MB) + B 8x128 rows x2 (1MB) = 2MB < 4MB L2,
// and all 64 of the XCD's blocks are co-resident (2/CU x 32CU) -> set stays live.
// (R9/R18 mapping gave each XCD ALL 32 nt -> 4MB B thrashed L2 -> FETCH 65.8MB and
// staging gates stalled on L3 latency. Rect mapping is FETCH 14.5MB-proven, R5/R6.)
// Loop body unchanged from R18 champion: 512 threads = 8 waves (wr = wid&3 M-quarter,
// sel = wid>>2 B1/B2), BK=64, LDS 64KB dbuf, pre-swizzled gload_lds, vmcnt(2) gate.
__global__ __launch_bounds__(512, 2) void k_fused(const s8* __restrict__ fn8,
                                                  const s8* __restrict__ fo8,
                                                  const int* __restrict__ tgt,
                                                  float* __restrict__ partial) {
  __shared__ __align__(16) s8 lA[2][256 * 64];   // 32 KB
  __shared__ __align__(16) s8 lB1[2][128 * 64];  // 16 KB
  __shared__ __align__(16) s8 lB2[2][128 * 64];  // 16 KB

  const int tid = threadIdx.x;
  const int lane = tid & 63;
  const int wid = tid >> 6;   // 0..7
  const int wr = wid & 3;     // M quarter
  const int sel = wid >> 2;   // 0: B1(old)  1: B2(new)
  const int lrow = lane & 15;
  const int lkg = lane >> 4;

  // XCD-rect mapping: grid 16mt x 32nt as 2x4 rects of 8x8 per XCD
  const int flat = blockIdx.x;
  const int x = flat & 7, loc = flat >> 3;        // xcd, local 0..63
  const int mt = (x >> 2) * 8 + (loc >> 3);       // 0..15
  const int nt = (x & 3) * 8 + (loc & 7);         // 0..31
  const int row0 = mt * 256, jb = nt * 128;

  // staging: chunk = 16 rows x 64 B = 64 lanes x 16 B. lane l covers row 16c+(l>>2),
  // phys slot l&3; fetch LOGICAL slot (l&3)^((l>>3)&3) so the linear LDS write lands
  // in read-swizzled position (read: slot' = slot ^ ((row>>1)&3), row = 16c+(l>>2)).
  const int crow = lane >> 2;
  const int cofs = 16 * ((lane & 3) ^ ((lane >> 3) & 3));

  auto stageA = [&](s8* dst, int kk) {
#pragma unroll
    for (int i = 0; i < 2; ++i) {
      const int c = wid * 2 + i;  // 16 chunks cover 256 A rows
      gload16(fn8 + (size_t)(row0 + c * 16 + crow) * DD + kk + cofs, dst + c * 1024);
    }
  };
  auto stageB = [&](s8* d1, s8* d2, int kk) {
    const int c = wid;  // 8 chunks cover 128 B rows
    gload16(fo8 + (size_t)(jb + c * 16 + crow) * DD + kk + cofs, d1 + c * 1024);
    gload16(fn8 + (size_t)(jb + c * 16 + crow) * DD + kk + cofs, d2 + c * 1024);
  };

  i32x4 acc[4][8];
#pragma unroll
  for (int a = 0; a < 4; ++a)
#pragma unroll
    for (int b = 0; b < 8; ++b) acc[a][b] = (i32x4)(0);

  // prologue: stage tile 0 (4 loads/wave in flight)
  stageA(lA[0], 0);
  stageB(lB1[0], lB2[0], 0);

  for (int t = 0; t < 8; ++t) {
    const int cur = t & 1, nxt = cur ^ 1;
    const s8* cA = lA[cur];
    const s8* cB = sel ? lB2[cur] : lB1[cur];

    if (t < 7) {
      stageA(lA[nxt], (t + 1) * 64);
      asm volatile("s_waitcnt vmcnt(2)" ::: "memory");  // tile t's 4 landed; 2 new fly on
    } else {
      asm volatile("s_waitcnt vmcnt(0)" ::: "memory");
    }
    barrier_raw();  // gate: tile t visible everywhere; prev reads done (end barrier)

    i32x4 av[4], bv[8];
#pragma unroll
    for (int f = 0; f < 4; ++f) {
      const int ar = wr * 64 + f * 16 + lrow;
      av[f] = *(const i32x4*)(cA + ar * 64 + ((lkg ^ ((ar >> 1) & 3)) * 16));
    }
#pragma unroll
    for (int f = 0; f < 8; ++f) {
      const int br = f * 16 + lrow;
      bv[f] = *(const i32x4*)(cB + br * 64 + ((lkg ^ ((br >> 1) & 3)) * 16));
    }
    if (t < 7) stageB(lB1[nxt], lB2[nxt], (t + 1) * 64);  // 2 more in flight for t+1
#pragma unroll
    for (int fr = 0; fr < 4; ++fr)
#pragma unroll
      for (int fc = 0; fc < 8; ++fc)
        acc[fr][fc] = __builtin_amdgcn_mfma_i32_16x16x64_i8(av[fr], bv[fc], acc[fr][fc], 0, 0, 0);
    barrier_raw();  // all waves done reading buf[cur] before t+1 overwrites it
  }

  // ---- epilogue: dequant + masked exp2, col-reduce, combine B1+B2, store partial ----
  const bool isN2O = (sel == 0);
  int tc[8];
#pragma unroll
  for (int fc = 0; fc < 8; ++fc) tc[fc] = tgt[jb + fc * 16 + lrow];
  float* rsum = (float*)lA;  // 2*256 floats; staging reads done
#pragma unroll
  for (int fr = 0; fr < 4; ++fr) {
#pragma unroll
    for (int reg = 0; reg < 4; ++reg) {
      const int gr = row0 + wr * 64 + fr * 16 + lkg * 4 + reg;
      const int trv = tgt[gr];
      float s = 0.0f;
#pragma unroll
      for (int fc = 0; fc < 8; ++fc) {
        const int gc = jb + fc * 16 + lrow;
        const float p = __builtin_amdgcn_exp2f(fmaf((float)acc[fr][fc][reg], CEXPQ, EOFF));
        // n2o: keep diagonal (stands in for the explicit pos column), drop same-label
        // n2n: drop all same-label (diagonal auto-dropped, labels equal)
        const bool keep = (trv != tc[fc]) || (isN2O && gr == gc);
        s += keep ? p : 0.0f;
      }
      s += __shfl_xor(s, 1);
      s += __shfl_xor(s, 2);
      s += __shfl_xor(s, 4);
      s += __shfl_xor(s, 8);
      if (lrow == 0) rsum[sel * 256 + wr * 64 + fr * 16 + lkg * 4 + reg] = s;
    }
  }
  asm volatile("s_waitcnt lgkmcnt(0)" ::: "memory");
  barrier_raw();
  if (tid < 256) {
    const float v = rsum[tid] + rsum[256 + tid];
    partial[(size_t)(row0 + tid) * 32 + nt] = v;
  }
}

// ---------------- kernel 3: per-row finalize + fused mean (32 blocks) ----------------
// Each block handles 128 rows; block total accumulated into out[0] via one atomicAdd
// per block (32 adds total; out zeroed by k_norm). Replaces separate k_final+k_mean.
__global__ __launch_bounds__(256) void k_final(const float* __restrict__ partial,
                                               const float* __restrict__ pos,
                                               float* __restrict__ out) {
  const int t = threadIdx.x;
  const int r = blockIdx.x * 128 + (t >> 1);
  const int half = t & 1;
  const float4* p = (const float4*)(partial + (size_t)r * 32 + half * 16);
  float v = 0.0f;
#pragma unroll
  for (int q = 0; q < 4; ++q) {
    const float4 a = p[q];
    v += (a.x + a.y) + (a.z + a.w);
  }
  v += __shfl_xor(v, 1);  // combine the two halves of the row
  float contrib = (half == 0)
                      ? (LSE_BASE + __builtin_amdgcn_logf(v) * LN2 - 100.0f * pos[r])
                      : 0.0f;
  contrib = wave_sum(contrib);
  __shared__ float red[4];
  if ((t & 63) == 0) red[t >> 6] = contrib;
  __syncthreads();
  if (t == 0)
    atomicAdd(out, ((red[0] + red[1]) + (red[2] + red[3])) * (1.0f / (float)BB));
}

extern "C" void kernel_launch(void* const* d_in, const int* in_sizes, int n_in,
                              void* d_out, int out_size, void* d_ws, size_t ws_size,
                              hipStream_t stream) {
  const float* feat = (const float*)d_in[0];
  const float* feat_old = (const float*)d_in[1];
  const int* targets = (const int*)d_in[2];
  float* out = (float*)d_out;
  char* ws = (char*)d_ws;

  s8* fn8 = (s8*)ws;                                             // 2 MB
  s8* fo8 = (s8*)(ws + 2u * 1024 * 1024);                        // 2 MB
  float* pos = (float*)(ws + 4u * 1024 * 1024);                  // 16 KB
  float* partial = (float*)(ws + 4u * 1024 * 1024 + 16 * 1024);  // 512 KB

  k_norm<<<BB / 4, 256, 0, stream>>>(feat, feat_old, fn8, fo8, pos, out);
  k_fused<<<512, 512, 0, stream>>>(fn8, fo8, targets, partial);
  k_final<<<32, 256, 0, stream>>>(partial, pos, out);
}

// Round 20
// 42.036 us; speedup vs baseline: 1.0216x; 1.0216x over previous
//
#include <hip/hip_runtime.h>
#include <hip/hip_bf16.h>

#define BB 4096
#define DD 512

typedef unsigned short u16;
typedef unsigned int u32;
typedef signed char s8;

using f32x4 = __attribute__((ext_vector_type(4))) float;
using i32x4 = __attribute__((ext_vector_type(4))) int;

// int8 quant: q = rint(x_norm * QS); exact i32 dot, s ~= acc / QS^2.
// p = exp2((s-1)*100*log2e + 64) = exp2(acc*CEXPQ + EOFF); lse = 100 - 64*ln2 + ln(sum p)
constexpr float QS = 400.0f;
constexpr float CEXP = 144.26950408889634f;          // 100 * log2(e)
constexpr float CEXPQ = CEXP / (QS * QS);            // dequant folded in
constexpr float EOFF = 64.0f - 144.26950408889634f;  // bias - CEXP
constexpr float LN2 = 0.6931471805599453f;
constexpr float LSE_BASE = 100.0f - 64.0f * 0.6931471805599453f;

__device__ __forceinline__ float wave_sum(float v) {
#pragma unroll
  for (int m = 1; m < 64; m <<= 1) v += __shfl_xor(v, m);
  return v;
}

// async global->LDS, 16B per lane. LDS dest is wave-uniform base + lane*16.
__device__ __forceinline__ void gload16(const void* g, const void* l) {
  __builtin_amdgcn_global_load_lds(
      (const __attribute__((address_space(1))) void*)g,
      (__attribute__((address_space(3))) void*)(const_cast<void*>(l)), 16, 0, 0);
}

// raw barrier (no vmcnt/lgkmcnt drain); memory clobbers pin memory ops to their side
__device__ __forceinline__ void barrier_raw() {
  asm volatile("" ::: "memory");
  __builtin_amdgcn_s_barrier();
  asm volatile("" ::: "memory");
}

__device__ __forceinline__ u32 q4(float a, float b, float c, float d, float s) {
  const int qa = (int)rintf(fminf(fmaxf(a * s, -127.0f), 127.0f));
  const int qb = (int)rintf(fminf(fmaxf(b * s, -127.0f), 127.0f));
  const int qc = (int)rintf(fminf(fmaxf(c * s, -127.0f), 127.0f));
  const int qd = (int)rintf(fminf(fmaxf(d * s, -127.0f), 127.0f));
  return (qa & 0xff) | ((qb & 0xff) << 8) | ((qc & 0xff) << 16) | ((qd & 0xff) << 24);
}

// ---------------- kernel 1: row L2-normalize (fp32) -> int8 (scale QS), fp32 pos ----------------
// Also zeroes out[0] each call (k_final accumulates into it atomically; keeps graph
// replays self-contained).
__global__ __launch_bounds__(256) void k_norm(const float* __restrict__ feat,
                                              const float* __restrict__ feat_old,
                                              s8* __restrict__ fn8, s8* __restrict__ fo8,
                                              float* __restrict__ pos,
                                              float* __restrict__ out) {
  if (blockIdx.x == 0 && threadIdx.x == 0) out[0] = 0.0f;
  const int i = blockIdx.x * 4 + (threadIdx.x >> 6);
  const int t = threadIdx.x & 63;
  const float4 x0 = *(const float4*)(feat + (size_t)i * DD + t * 4);
  const float4 x1 = *(const float4*)(feat + (size_t)i * DD + 256 + t * 4);
  const float4 y0 = *(const float4*)(feat_old + (size_t)i * DD + t * 4);
  const float4 y1 = *(const float4*)(feat_old + (size_t)i * DD + 256 + t * 4);
  float sx = x0.x * x0.x + x0.y * x0.y + x0.z * x0.z + x0.w * x0.w +
             x1.x * x1.x + x1.y * x1.y + x1.z * x1.z + x1.w * x1.w;
  float sy = y0.x * y0.x + y0.y * y0.y + y0.z * y0.z + y0.w * y0.w +
             y1.x * y1.x + y1.y * y1.y + y1.z * y1.z + y1.w * y1.w;
  float sxy = x0.x * y0.x + x0.y * y0.y + x0.z * y0.z + x0.w * y0.w +
              x1.x * y1.x + x1.y * y1.y + x1.z * y1.z + x1.w * y1.w;
  sx = wave_sum(sx);
  sy = wave_sum(sy);
  sxy = wave_sum(sxy);
  const float inx = 1.0f / fmaxf(sqrtf(sx), 1e-12f);
  const float iny = 1.0f / fmaxf(sqrtf(sy), 1e-12f);
  const float sxq = inx * QS, syq = iny * QS;
  u32* px0 = (u32*)(fn8 + (size_t)i * DD + t * 4);
  u32* px1 = (u32*)(fn8 + (size_t)i * DD + 256 + t * 4);
  u32* py0 = (u32*)(fo8 + (size_t)i * DD + t * 4);
  u32* py1 = (u32*)(fo8 + (size_t)i * DD + 256 + t * 4);
  *px0 = q4(x0.x, x0.y, x0.z, x0.w, sxq);
  *px1 = q4(x1.x, x1.y, x1.z, x1.w, sxq);
  *py0 = q4(y0.x, y0.y, y0.z, y0.w, syq);
  *py1 = q4(y1.x, y1.y, y1.z, y1.w, syq);
  if (t == 0) pos[i] = sxy * inx * iny;  // exact fp32 positive logit
}

// ---------------- kernel 2: fused dual-GEMM, int8 MFMA (R18 champion) ----------------
// 512 blocks = 16 mt x 32 nt (XCD-swizzled, exactly 2 rounds of 256 CUs - no tail).
// 512 threads = 8 waves: wr = wid&3 (64-row M quarter), sel = wid>>2 (B1=old / B2=new).
// Tile: A 256xK, B 128xK each. BK=64 -> 32 mfma_i32_16x16x64_i8 per wave per K-tile.
// LDS 64 KB dbuf; VGPR 128 -> 2 blocks/CU co-resident. No setprio (m190: negative on
// lockstep schedules). R19 A/B: XCD-rect mapping null -> champion is FETCH-insensitive.
__global__ __launch_bounds__(512, 2) void k_fused(const s8* __restrict__ fn8,
                                                  const s8* __restrict__ fo8,
                                                  const int* __restrict__ tgt,
                                                  float* __restrict__ partial) {
  __shared__ __align__(16) s8 lA[2][256 * 64];   // 32 KB
  __shared__ __align__(16) s8 lB1[2][128 * 64];  // 16 KB
  __shared__ __align__(16) s8 lB2[2][128 * 64];  // 16 KB

  const int tid = threadIdx.x;
  const int lane = tid & 63;
  const int wid = tid >> 6;   // 0..7
  const int wr = wid & 3;     // M quarter
  const int sel = wid >> 2;   // 0: B1(old)  1: B2(new)
  const int lrow = lane & 15;
  const int lkg = lane >> 4;

  // XCD-aware bijective swizzle (512 % 8 == 0)
  const int flat = blockIdx.x;
  const int swz = (flat & 7) * 64 + (flat >> 3);
  const int mt = swz >> 5, nt = swz & 31;
  const int row0 = mt * 256, jb = nt * 128;

  // staging: chunk = 16 rows x 64 B = 64 lanes x 16 B. lane l covers row 16c+(l>>2),
  // phys slot l&3; fetch LOGICAL slot (l&3)^((l>>3)&3) so the linear LDS write lands
  // in read-swizzled position (read: slot' = slot ^ ((row>>1)&3), row = 16c+(l>>2)).
  const int crow = lane >> 2;
  const int cofs = 16 * ((lane & 3) ^ ((lane >> 3) & 3));

  auto stageA = [&](s8* dst, int kk) {
#pragma unroll
    for (int i = 0; i < 2; ++i) {
      const int c = wid * 2 + i;  // 16 chunks cover 256 A rows
      gload16(fn8 + (size_t)(row0 + c * 16 + crow) * DD + kk + cofs, dst + c * 1024);
    }
  };
  auto stageB = [&](s8* d1, s8* d2, int kk) {
    const int c = wid;  // 8 chunks cover 128 B rows
    gload16(fo8 + (size_t)(jb + c * 16 + crow) * DD + kk + cofs, d1 + c * 1024);
    gload16(fn8 + (size_t)(jb + c * 16 + crow) * DD + kk + cofs, d2 + c * 1024);
  };

  i32x4 acc[4][8];
#pragma unroll
  for (int a = 0; a < 4; ++a)
#pragma unroll
    for (int b = 0; b < 8; ++b) acc[a][b] = (i32x4)(0);

  // prologue: stage tile 0 (4 loads/wave in flight)
  stageA(lA[0], 0);
  stageB(lB1[0], lB2[0], 0);

  for (int t = 0; t < 8; ++t) {
    const int cur = t & 1, nxt = cur ^ 1;
    const s8* cA = lA[cur];
    const s8* cB = sel ? lB2[cur] : lB1[cur];

    if (t < 7) {
      stageA(lA[nxt], (t + 1) * 64);
      asm volatile("s_waitcnt vmcnt(2)" ::: "memory");  // tile t's 4 landed; 2 new fly on
    } else {
      asm volatile("s_waitcnt vmcnt(0)" ::: "memory");
    }
    barrier_raw();  // gate: tile t visible everywhere; prev reads done (end barrier)

    i32x4 av[4], bv[8];
#pragma unroll
    for (int f = 0; f < 4; ++f) {
      const int ar = wr * 64 + f * 16 + lrow;
      av[f] = *(const i32x4*)(cA + ar * 64 + ((lkg ^ ((ar >> 1) & 3)) * 16));
    }
#pragma unroll
    for (int f = 0; f < 8; ++f) {
      const int br = f * 16 + lrow;
      bv[f] = *(const i32x4*)(cB + br * 64 + ((lkg ^ ((br >> 1) & 3)) * 16));
    }
    if (t < 7) stageB(lB1[nxt], lB2[nxt], (t + 1) * 64);  // 2 more in flight for t+1
#pragma unroll
    for (int fr = 0; fr < 4; ++fr)
#pragma unroll
      for (int fc = 0; fc < 8; ++fc)
        acc[fr][fc] = __builtin_amdgcn_mfma_i32_16x16x64_i8(av[fr], bv[fc], acc[fr][fc], 0, 0, 0);
    barrier_raw();  // all waves done reading buf[cur] before t+1 overwrites it
  }

  // ---- epilogue: dequant + masked exp2, col-reduce, combine B1+B2, store partial ----
  const bool isN2O = (sel == 0);
  int tc[8];
#pragma unroll
  for (int fc = 0; fc < 8; ++fc) tc[fc] = tgt[jb + fc * 16 + lrow];
  float* rsum = (float*)lA;  // 2*256 floats; staging reads done
#pragma unroll
  for (int fr = 0; fr < 4; ++fr) {
#pragma unroll
    for (int reg = 0; reg < 4; ++reg) {
      const int gr = row0 + wr * 64 + fr * 16 + lkg * 4 + reg;
      const int trv = tgt[gr];
      float s = 0.0f;
#pragma unroll
      for (int fc = 0; fc < 8; ++fc) {
        const int gc = jb + fc * 16 + lrow;
        const float p = __builtin_amdgcn_exp2f(fmaf((float)acc[fr][fc][reg], CEXPQ, EOFF));
        // n2o: keep diagonal (stands in for the explicit pos column), drop same-label
        // n2n: drop all same-label (diagonal auto-dropped, labels equal)
        const bool keep = (trv != tc[fc]) || (isN2O && gr == gc);
        s += keep ? p : 0.0f;
      }
      s += __shfl_xor(s, 1);
      s += __shfl_xor(s, 2);
      s += __shfl_xor(s, 4);
      s += __shfl_xor(s, 8);
      if (lrow == 0) rsum[sel * 256 + wr * 64 + fr * 16 + lkg * 4 + reg] = s;
    }
  }
  asm volatile("s_waitcnt lgkmcnt(0)" ::: "memory");
  barrier_raw();
  if (tid < 256) {
    const float v = rsum[tid] + rsum[256 + tid];
    partial[(size_t)(row0 + tid) * 32 + nt] = v;
  }
}

// ---------------- kernel 3: per-row finalize + fused mean (32 blocks) ----------------
// Each block handles 128 rows; block total accumulated into out[0] via one atomicAdd
// per block (32 adds total; out zeroed by k_norm). Replaces separate k_final+k_mean.
__global__ __launch_bounds__(256) void k_final(const float* __restrict__ partial,
                                               const float* __restrict__ pos,
                                               float* __restrict__ out) {
  const int t = threadIdx.x;
  const int r = blockIdx.x * 128 + (t >> 1);
  const int half = t & 1;
  const float4* p = (const float4*)(partial + (size_t)r * 32 + half * 16);
  float v = 0.0f;
#pragma unroll
  for (int q = 0; q < 4; ++q) {
    const float4 a = p[q];
    v += (a.x + a.y) + (a.z + a.w);
  }
  v += __shfl_xor(v, 1);  // combine the two halves of the row
  float contrib = (half == 0)
                      ? (LSE_BASE + __builtin_amdgcn_logf(v) * LN2 - 100.0f * pos[r])
                      : 0.0f;
  contrib = wave_sum(contrib);
  __shared__ float red[4];
  if ((t & 63) == 0) red[t >> 6] = contrib;
  __syncthreads();
  if (t == 0)
    atomicAdd(out, ((red[0] + red[1]) + (red[2] + red[3])) * (1.0f / (float)BB));
}

extern "C" void kernel_launch(void* const* d_in, const int* in_sizes, int n_in,
                              void* d_out, int out_size, void* d_ws, size_t ws_size,
                              hipStream_t stream) {
  const float* feat = (const float*)d_in[0];
  const float* feat_old = (const float*)d_in[1];
  const int* targets = (const int*)d_in[2];
  float* out = (float*)d_out;
  char* ws = (char*)d_ws;

  s8* fn8 = (s8*)ws;                                             // 2 MB
  s8* fo8 = (s8*)(ws + 2u * 1024 * 1024);                        // 2 MB
  float* pos = (float*)(ws + 4u * 1024 * 1024);                  // 16 KB
  float* partial = (float*)(ws + 4u * 1024 * 1024 + 16 * 1024);  // 512 KB

  k_norm<<<BB / 4, 256, 0, stream>>>(feat, feat_old, fn8, fo8, pos, out);
  k_fused<<<512, 512, 0, stream>>>(fn8, fo8, targets, partial);
  k_final<<<32, 256, 0, stream>>>(partial, pos, out);
}